// Round 1
// baseline (951.799 us; speedup 1.0000x reference)
//
#include <hip/hip_runtime.h>

// Problem constants (fixed by the reference file).
static constexpr int B = 16;
static constexpr int N = 250000;
static constexpr int F = 500000;

// Workspace layout:
//   acc : float[N][48]  (vertex-major; 16 batches x 3 comps, 192 B per vertex row) = 48 MB
//   deg : uint[N]                                                                  =  1 MB
// Total 49 MB, zeroed each call via hipMemsetAsync (ws is re-poisoned to 0xAA).

__global__ __launch_bounds__(256) void uls_scatter(
    const float* __restrict__ vert,   // (B, N, 3)
    const int*   __restrict__ faces,  // (F, 3)
    float*       __restrict__ acc,    // (N, 16, 3)
    unsigned int* __restrict__ deg)   // (N,)
{
    int idx = blockIdx.x * 256 + threadIdx.x;
    if (idx >= F * B) return;
    int f     = idx >> 4;   // face id   (wave = 4 faces x 16 batches)
    int batch = idx & 15;   // batch id

    int i0 = faces[f * 3 + 0];
    int i1 = faces[f * 3 + 1];
    int i2 = faces[f * 3 + 2];

    const float* vb = vert + (size_t)batch * (N * 3);
    float p0x = vb[i0 * 3 + 0], p0y = vb[i0 * 3 + 1], p0z = vb[i0 * 3 + 2];
    float p1x = vb[i1 * 3 + 0], p1y = vb[i1 * 3 + 1], p1z = vb[i1 * 3 + 2];
    float p2x = vb[i2 * 3 + 0], p2y = vb[i2 * 3 + 1], p2z = vb[i2 * 3 + 2];

    float* a0 = acc + (size_t)i0 * 48 + batch * 3;
    float* a1 = acc + (size_t)i1 * 48 + batch * 3;
    float* a2 = acc + (size_t)i2 * 48 + batch * 3;

    // Per face: vertex a receives b+c, b receives a+c, c receives a+b.
    // unsafeAtomicAdd -> hardware global_atomic_add_f32 (no CAS loop);
    // d_ws is coarse-grained device memory so this is exact fp32 add.
    unsafeAtomicAdd(a0 + 0, p1x + p2x);
    unsafeAtomicAdd(a0 + 1, p1y + p2y);
    unsafeAtomicAdd(a0 + 2, p1z + p2z);
    unsafeAtomicAdd(a1 + 0, p0x + p2x);
    unsafeAtomicAdd(a1 + 1, p0y + p2y);
    unsafeAtomicAdd(a1 + 2, p0z + p2z);
    unsafeAtomicAdd(a2 + 0, p0x + p1x);
    unsafeAtomicAdd(a2 + 1, p0y + p1y);
    unsafeAtomicAdd(a2 + 2, p0z + p1z);

    if (batch == 0) {
        // Each face contributes 2 incident directed edges per vertex.
        atomicAdd(&deg[i0], 2u);
        atomicAdd(&deg[i1], 2u);
        atomicAdd(&deg[i2], 2u);
    }
}

__global__ __launch_bounds__(256) void uls_finalize(
    const float* __restrict__ vert,   // (B, N, 3)
    const float* __restrict__ acc,    // (N, 16, 3)
    const unsigned int* __restrict__ deg,
    float* __restrict__ out)          // (B, N)
{
    int idx = blockIdx.x * 256 + threadIdx.x;
    if (idx >= B * N) return;
    int batch = idx / N;
    int n     = idx - batch * N;

    float d = (float)deg[n];
    d = fmaxf(d, 1.0f);
    float inv = 1.0f / d;

    const float* a = acc  + (size_t)n * 48 + batch * 3;
    const float* v = vert + (size_t)batch * (N * 3) + (size_t)n * 3;

    float lx = a[0] * inv - v[0];
    float ly = a[1] * inv - v[1];
    float lz = a[2] * inv - v[2];
    out[idx] = sqrtf(lx * lx + ly * ly + lz * lz);
}

extern "C" void kernel_launch(void* const* d_in, const int* in_sizes, int n_in,
                              void* d_out, int out_size, void* d_ws, size_t ws_size,
                              hipStream_t stream) {
    const float* vert  = (const float*)d_in[0];   // (B, N, 3) fp32
    const int*   faces = (const int*)d_in[1];     // (F, 3) int32
    float* out = (float*)d_out;                   // (B, N) fp32

    float*        acc = (float*)d_ws;                                  // N*48 floats
    unsigned int* deg = (unsigned int*)((char*)d_ws + (size_t)N * 48 * sizeof(float));

    const size_t zero_bytes = (size_t)N * 48 * sizeof(float) + (size_t)N * sizeof(unsigned int);
    hipMemsetAsync(d_ws, 0, zero_bytes, stream);

    {
        const int total = F * B;                  // 8,000,000
        uls_scatter<<<total / 256, 256, 0, stream>>>(vert, faces, acc, deg);
    }
    {
        const int total = B * N;                  // 4,000,000
        uls_finalize<<<total / 256, 256, 0, stream>>>(vert, acc, deg, out);
    }
}

// Round 2
// 345.513 us; speedup vs baseline: 2.7547x; 2.7547x over previous
//
#include <hip/hip_runtime.h>

// Problem constants (fixed by the reference file).
static constexpr int B = 16;
static constexpr int N = 250000;   // 250000 = 15625 * 16
static constexpr int F = 500000;
static constexpr int ROW = 48;     // floats per vertex row: 16 batches * 3 comps (192 B)
static constexpr int E = 6 * F;    // directed edges = 3,000,000 (always even per vertex)

// ---- Plan B workspace layout (bytes) ----
//   vt      : float[N][48]   48,000,000   vertex-major positions
//   adj     : int[E]         12,000,000   CSR adjacency values (src ids)
//   deg     : uint[N]         1,000,000
//   cursor  : uint[N]         1,000,000
//   counter : uint                    4
//   start   : uint[N]         1,000,000
static constexpr size_t OFF_VT  = 0;
static constexpr size_t OFF_ADJ = (size_t)N * ROW * sizeof(float);        // 48,000,000
static constexpr size_t OFF_DEG = OFF_ADJ + (size_t)E * sizeof(int);      // 60,000,000
static constexpr size_t OFF_CUR = OFF_DEG + (size_t)N * sizeof(unsigned); // 61,000,000
static constexpr size_t OFF_CNT = OFF_CUR + (size_t)N * sizeof(unsigned); // 62,000,000
static constexpr size_t OFF_STA = OFF_CNT + 256;                          // 62,000,256 (aligned)
static constexpr size_t WS_NEED = OFF_STA + (size_t)N * sizeof(unsigned); // ~63 MB

// ---------------- Plan B kernels ----------------

// (B,N,3) -> (N,16,3): 16 vertices per block, fully coalesced both sides via LDS.
__global__ __launch_bounds__(256) void uls_transpose(
    const float* __restrict__ vert, float* __restrict__ vt)
{
    __shared__ float lds[16 * ROW];  // 768 floats
    int t = threadIdx.x;
    int n0 = blockIdx.x * 16;
    int b = t >> 4, v = t & 15;
    const float* s = vert + (size_t)b * (N * 3) + (size_t)(n0 + v) * 3;
    lds[v * ROW + b * 3 + 0] = s[0];
    lds[v * ROW + b * 3 + 1] = s[1];
    lds[v * ROW + b * 3 + 2] = s[2];
    __syncthreads();
    float* d = vt + (size_t)n0 * ROW;  // 768 contiguous floats
    d[t * 3 + 0] = lds[t * 3 + 0];
    d[t * 3 + 1] = lds[t * 3 + 1];
    d[t * 3 + 2] = lds[t * 3 + 2];
}

__global__ __launch_bounds__(256) void uls_count(
    const int* __restrict__ faces, unsigned* __restrict__ deg)
{
    int f = blockIdx.x * 256 + threadIdx.x;
    if (f >= F) return;
    int a = faces[3 * f + 0], b = faces[3 * f + 1], c = faces[3 * f + 2];
    atomicAdd(&deg[a], 2u);
    atomicAdd(&deg[b], 2u);
    atomicAdd(&deg[c], 2u);
}

// start[n] = block-local exclusive scan + atomically allocated block base.
// Cross-block ordering is arbitrary — irrelevant, regions just need to be disjoint.
__global__ __launch_bounds__(256) void uls_alloc(
    const unsigned* __restrict__ deg, unsigned* __restrict__ start,
    unsigned* __restrict__ counter)
{
    __shared__ unsigned s[256];
    __shared__ unsigned base;
    int t = threadIdx.x;
    int n = blockIdx.x * 256 + t;
    unsigned d = (n < N) ? deg[n] : 0u;
    s[t] = d;
    __syncthreads();
    for (int off = 1; off < 256; off <<= 1) {     // Hillis-Steele inclusive scan
        unsigned v = (t >= off) ? s[t - off] : 0u;
        __syncthreads();
        s[t] += v;
        __syncthreads();
    }
    if (t == 255) base = atomicAdd(counter, s[255]);
    __syncthreads();
    if (n < N) start[n] = base + (s[t] - d);      // exclusive = inclusive - self
}

__global__ __launch_bounds__(256) void uls_fill(
    const int* __restrict__ faces, const unsigned* __restrict__ start,
    unsigned* __restrict__ cursor, int* __restrict__ adj)
{
    int f = blockIdx.x * 256 + threadIdx.x;
    if (f >= F) return;
    int a = faces[3 * f + 0], b = faces[3 * f + 1], c = faces[3 * f + 2];
    unsigned p;
    p = atomicAdd(&cursor[a], 2u); adj[start[a] + p] = b; adj[start[a] + p + 1] = c;
    p = atomicAdd(&cursor[b], 2u); adj[start[b] + p] = a; adj[start[b] + p + 1] = c;
    p = atomicAdd(&cursor[c], 2u); adj[start[c] + p] = a; adj[start[c] + p + 1] = b;
}

// 16 lanes share a vertex and span batches 0..15 -> every neighbor-row read is
// a coalesced 192 B (3 full lines, all bytes used). No atomics anywhere.
__global__ __launch_bounds__(256) void uls_gather(
    const float* __restrict__ vt, const int* __restrict__ adj,
    const unsigned* __restrict__ start, const unsigned* __restrict__ deg,
    float* __restrict__ out)
{
    __shared__ float lds[16 * 17];   // +1 pad: conflict-free transpose
    int t = threadIdx.x;
    int b = t & 15, v = t >> 4;
    int n = blockIdx.x * 16 + v;

    unsigned s0 = start[n];          // uniform per 16-lane group (broadcast)
    unsigned d  = deg[n];

    float ax = 0.f, ay = 0.f, az = 0.f;
    // degree is always even; unroll x2 for two independent row loads in flight
    for (unsigned j = 0; j < d; j += 2) {
        int2 sp = *(const int2*)(adj + s0 + j);   // s0 even -> 8 B aligned
        const float* r0 = vt + (size_t)sp.x * ROW + b * 3;
        const float* r1 = vt + (size_t)sp.y * ROW + b * 3;
        float x0 = r0[0], y0 = r0[1], z0 = r0[2];
        float x1 = r1[0], y1 = r1[1], z1 = r1[2];
        ax += x0 + x1; ay += y0 + y1; az += z0 + z1;
    }
    const float* rs = vt + (size_t)n * ROW + b * 3;
    float inv = 1.0f / fmaxf((float)d, 1.0f);
    float lx = ax * inv - rs[0];
    float ly = ay * inv - rs[1];
    float lz = az * inv - rs[2];
    lds[v * 17 + b] = sqrtf(lx * lx + ly * ly + lz * lz);
    __syncthreads();
    int vo = t & 15, bo = t >> 4;
    out[(size_t)bo * N + blockIdx.x * 16 + vo] = lds[vo * 17 + bo];  // coalesced
}

// ---------------- Plan A fallback (round-1 scatter; used only if ws too small) ----------------

__global__ __launch_bounds__(256) void uls_scatter(
    const float* __restrict__ vert, const int* __restrict__ faces,
    float* __restrict__ acc, unsigned int* __restrict__ deg)
{
    int idx = blockIdx.x * 256 + threadIdx.x;
    if (idx >= F * B) return;
    int f = idx >> 4, batch = idx & 15;
    int i0 = faces[f * 3 + 0], i1 = faces[f * 3 + 1], i2 = faces[f * 3 + 2];
    const float* vb = vert + (size_t)batch * (N * 3);
    float p0x = vb[i0 * 3 + 0], p0y = vb[i0 * 3 + 1], p0z = vb[i0 * 3 + 2];
    float p1x = vb[i1 * 3 + 0], p1y = vb[i1 * 3 + 1], p1z = vb[i1 * 3 + 2];
    float p2x = vb[i2 * 3 + 0], p2y = vb[i2 * 3 + 1], p2z = vb[i2 * 3 + 2];
    float* a0 = acc + (size_t)i0 * 48 + batch * 3;
    float* a1 = acc + (size_t)i1 * 48 + batch * 3;
    float* a2 = acc + (size_t)i2 * 48 + batch * 3;
    unsafeAtomicAdd(a0 + 0, p1x + p2x); unsafeAtomicAdd(a0 + 1, p1y + p2y); unsafeAtomicAdd(a0 + 2, p1z + p2z);
    unsafeAtomicAdd(a1 + 0, p0x + p2x); unsafeAtomicAdd(a1 + 1, p0y + p2y); unsafeAtomicAdd(a1 + 2, p0z + p2z);
    unsafeAtomicAdd(a2 + 0, p0x + p1x); unsafeAtomicAdd(a2 + 1, p0y + p1y); unsafeAtomicAdd(a2 + 2, p0z + p1z);
    if (batch == 0) {
        atomicAdd(&deg[i0], 2u); atomicAdd(&deg[i1], 2u); atomicAdd(&deg[i2], 2u);
    }
}

__global__ __launch_bounds__(256) void uls_finalize(
    const float* __restrict__ vert, const float* __restrict__ acc,
    const unsigned int* __restrict__ deg, float* __restrict__ out)
{
    int idx = blockIdx.x * 256 + threadIdx.x;
    if (idx >= B * N) return;
    int batch = idx / N;
    int n = idx - batch * N;
    float d = fmaxf((float)deg[n], 1.0f);
    float inv = 1.0f / d;
    const float* a = acc + (size_t)n * 48 + batch * 3;
    const float* v = vert + (size_t)batch * (N * 3) + (size_t)n * 3;
    float lx = a[0] * inv - v[0];
    float ly = a[1] * inv - v[1];
    float lz = a[2] * inv - v[2];
    out[idx] = sqrtf(lx * lx + ly * ly + lz * lz);
}

// ---------------- launcher ----------------

extern "C" void kernel_launch(void* const* d_in, const int* in_sizes, int n_in,
                              void* d_out, int out_size, void* d_ws, size_t ws_size,
                              hipStream_t stream) {
    const float* vert  = (const float*)d_in[0];   // (B, N, 3) fp32
    const int*   faces = (const int*)d_in[1];     // (F, 3) int32
    float* out = (float*)d_out;                   // (B, N) fp32
    char* ws = (char*)d_ws;

    if (ws_size >= WS_NEED) {
        float*    vt      = (float*)(ws + OFF_VT);
        int*      adj     = (int*)(ws + OFF_ADJ);
        unsigned* deg     = (unsigned*)(ws + OFF_DEG);
        unsigned* cursor  = (unsigned*)(ws + OFF_CUR);
        unsigned* counter = (unsigned*)(ws + OFF_CNT);
        unsigned* start   = (unsigned*)(ws + OFF_STA);

        // zero deg + cursor + counter in one contiguous memset
        hipMemsetAsync(ws + OFF_DEG, 0, (OFF_CNT + 256) - OFF_DEG, stream);

        uls_transpose<<<N / 16, 256, 0, stream>>>(vert, vt);
        uls_count<<<(F + 255) / 256, 256, 0, stream>>>(faces, deg);
        uls_alloc<<<(N + 255) / 256, 256, 0, stream>>>(deg, start, counter);
        uls_fill<<<(F + 255) / 256, 256, 0, stream>>>(faces, start, cursor, adj);
        uls_gather<<<N / 16, 256, 0, stream>>>(vt, adj, start, deg, out);
    } else {
        // Fallback: round-1 scatter (needs 49 MB)
        float*        acc = (float*)ws;
        unsigned int* deg = (unsigned int*)(ws + (size_t)N * 48 * sizeof(float));
        hipMemsetAsync(ws, 0, (size_t)N * 48 * sizeof(float) + (size_t)N * sizeof(unsigned), stream);
        uls_scatter<<<(F * B) / 256, 256, 0, stream>>>(vert, faces, acc, deg);
        uls_finalize<<<(B * N) / 256, 256, 0, stream>>>(vert, acc, deg, out);
    }
}